// Round 2
// baseline (436.614 us; speedup 1.0000x reference)
//
#include <hip/hip_runtime.h>
#include <math.h>

#define NNODES 50000
#define FIN 256
#define HH 4
#define CC 32
#define D1 128   // H*C
#define CLS 16

__device__ __forceinline__ float lrelu(float x){ return x > 0.f ? x : 0.2f*x; }

// ---------------- GEMM1: h1 = x @ W1   [N,256] x [256,128] ----------------
__global__ __launch_bounds__(256) void gemm1_kernel(const float* __restrict__ x,
                                                    const float* __restrict__ W,
                                                    float* __restrict__ h1) {
  __shared__ float xs[32][64];
  __shared__ float ws[32][128];
  int r0 = blockIdx.x * 64;
  int tid = threadIdx.x;
  int tx = tid & 15, ty = tid >> 4;
  float acc[4][8];
  #pragma unroll
  for (int i=0;i<4;i++)
    #pragma unroll
    for (int j=0;j<8;j++) acc[i][j]=0.f;
  for (int k0 = 0; k0 < FIN; k0 += 32) {
    {
      int row = tid >> 3, kq = tid & 7;
      #pragma unroll
      for (int rr = 0; rr < 2; rr++) {          // FIX: 64 rows, 2 per thread
        int r = row + rr*32;
        int gr = r0 + r;
        float4 v = make_float4(0.f,0.f,0.f,0.f);
        if (gr < NNODES) v = *(const float4*)(x + (size_t)gr*FIN + k0 + kq*4);
        xs[kq*4+0][r] = v.x; xs[kq*4+1][r] = v.y;
        xs[kq*4+2][r] = v.z; xs[kq*4+3][r] = v.w;
      }
    }
    #pragma unroll
    for (int it=0; it<4; it++) {
      int l = it*1024 + tid*4;
      int k = l >> 7, c = l & 127;
      float4 v = *(const float4*)(W + (size_t)(k0+k)*D1 + c);
      *(float4*)(&ws[k][c]) = v;
    }
    __syncthreads();
    #pragma unroll
    for (int k=0;k<32;k++) {
      float xv[4], wv[8];
      #pragma unroll
      for (int i=0;i<4;i++) xv[i] = xs[k][ty*4+i];
      #pragma unroll
      for (int j=0;j<8;j++) wv[j] = ws[k][tx*8+j];
      #pragma unroll
      for (int i=0;i<4;i++)
        #pragma unroll
        for (int j=0;j<8;j++)
          acc[i][j] = fmaf(xv[i], wv[j], acc[i][j]);
    }
    __syncthreads();
  }
  #pragma unroll
  for (int i=0;i<4;i++) {
    int gr = r0 + ty*4 + i;
    if (gr < NNODES) {
      #pragma unroll
      for (int j=0;j<8;j+=4) {
        float4 v = make_float4(acc[i][j],acc[i][j+1],acc[i][j+2],acc[i][j+3]);
        *(float4*)(h1 + (size_t)gr*D1 + tx*8 + j) = v;
      }
    }
  }
}

// ---------------- per-node alpha for layer 1 ----------------
__global__ void alpha1_kernel(const float* __restrict__ h1,
                              const float* __restrict__ asrc,
                              const float* __restrict__ adst,
                              float* __restrict__ as1, float* __restrict__ ad1) {
  int t = blockIdx.x * blockDim.x + threadIdx.x;  // i*H + h
  if (t >= NNODES*HH) return;
  int i = t >> 2, h = t & 3;
  const float* hp = h1 + (size_t)i*D1 + h*CC;
  const float* ap = asrc + h*CC;
  const float* bp = adst + h*CC;
  float s=0.f, d=0.f;
  #pragma unroll
  for (int c=0;c<CC;c++){ float v = hp[c]; s = fmaf(v, ap[c], s); d = fmaf(v, bp[c], d); }
  as1[t] = s; ad1[t] = d;
}

// ---------------- CSR build (by dst) ----------------
__global__ void count_kernel(const int* __restrict__ dsts, int* deg, int E) {
  int e = blockIdx.x*blockDim.x + threadIdx.x;
  if (e < E) atomicAdd(&deg[dsts[e]], 1);
}

__global__ __launch_bounds__(1024) void scan_kernel(const int* __restrict__ deg,
                                                    int* __restrict__ offs) {
  __shared__ int buf[1024];
  __shared__ int base;
  if (threadIdx.x == 0){ base = 0; offs[0] = 0; }
  __syncthreads();
  for (int c = 0; c < NNODES; c += 1024) {
    int i = c + threadIdx.x;
    int v = (i < NNODES) ? deg[i] : 0;
    buf[threadIdx.x] = v;
    __syncthreads();
    for (int off=1; off<1024; off<<=1) {
      int t = (threadIdx.x >= off) ? buf[threadIdx.x - off] : 0;
      __syncthreads();
      buf[threadIdx.x] += t;
      __syncthreads();
    }
    if (i < NNODES) offs[i+1] = base + buf[threadIdx.x];
    __syncthreads();
    if (threadIdx.x == 0) base += buf[1023];
    __syncthreads();
  }
}

__global__ void cursor_kernel(const int* __restrict__ offs, int* cursor) {
  int i = blockIdx.x*blockDim.x + threadIdx.x;
  if (i < NNODES) cursor[i] = offs[i];
}

__global__ void place_kernel(const int* __restrict__ srcs, const int* __restrict__ dsts,
                             int* cursor, int* __restrict__ srcsort, int E) {
  int e = blockIdx.x*blockDim.x + threadIdx.x;
  if (e < E) {
    int d = dsts[e];
    int p = atomicAdd(&cursor[d], 1);
    srcsort[p] = srcs[e];
  }
}

// ---------------- layer-1 segment softmax + aggregation (+bias+ELU) ----------------
__global__ __launch_bounds__(256) void agg1_kernel(
    const float* __restrict__ h1, const float* __restrict__ as1,
    const float* __restrict__ ad1, const int* __restrict__ offs,
    const int* __restrict__ srcsort, const float* __restrict__ b1,
    float* __restrict__ out1) {
  int warp = threadIdx.x >> 6;
  int lane = threadIdx.x & 63;
  int i = blockIdx.x * 4 + warp;
  if (i >= NNODES) return;
  int start = offs[i], end = offs[i+1];
  float ad[4], sself[4], m[4];
  #pragma unroll
  for (int h=0;h<4;h++) ad[h] = ad1[i*4+h];
  #pragma unroll
  for (int h=0;h<4;h++) { sself[h] = lrelu(as1[i*4+h] + ad[h]); m[h] = sself[h]; }
  // pass1: max over incoming edges
  for (int j = start + lane; j < end; j += 64) {
    int s = srcsort[j];
    #pragma unroll
    for (int h=0;h<4;h++) m[h] = fmaxf(m[h], lrelu(as1[s*4+h] + ad[h]));
  }
  #pragma unroll
  for (int off=1; off<64; off<<=1) {
    #pragma unroll
    for (int h=0;h<4;h++) m[h] = fmaxf(m[h], __shfl_xor(m[h], off, 64));
  }
  // pass2: denominator
  float den[4];
  #pragma unroll
  for (int h=0;h<4;h++) den[h] = (lane==0) ? expf(sself[h]-m[h]) : 0.f;
  for (int j = start + lane; j < end; j += 64) {
    int s = srcsort[j];
    #pragma unroll
    for (int h=0;h<4;h++) den[h] += expf(lrelu(as1[s*4+h] + ad[h]) - m[h]);
  }
  #pragma unroll
  for (int off=1; off<64; off<<=1) {
    #pragma unroll
    for (int h=0;h<4;h++) den[h] += __shfl_xor(den[h], off, 64);
  }
  float inv[4];
  #pragma unroll
  for (int h=0;h<4;h++) inv[h] = 1.f / (den[h] + 1e-16f);
  // pass3: weighted aggregation. lane owns flat channels lane and lane+64.
  int hlo = lane >> 5;     // head of channel `lane`   (0 or 1)
  int hhi = hlo + 2;       // head of channel lane+64  (2 or 3)
  float mlo = m[hlo], mhi = m[hhi], adlo = ad[hlo], adhi = ad[hhi];
  float invlo = inv[hlo], invhi = inv[hhi];
  float wslo = expf(sself[hlo]-mlo)*invlo;
  float wshi = expf(sself[hhi]-mhi)*invhi;
  float acc0 = wslo * h1[(size_t)i*D1 + lane];
  float acc1 = wshi * h1[(size_t)i*D1 + 64 + lane];
  for (int j = start; j < end; j++) {
    int s = srcsort[j];
    float w0 = expf(lrelu(as1[s*4+hlo] + adlo) - mlo) * invlo;
    float w1 = expf(lrelu(as1[s*4+hhi] + adhi) - mhi) * invhi;
    acc0 = fmaf(w0, h1[(size_t)s*D1 + lane],      acc0);
    acc1 = fmaf(w1, h1[(size_t)s*D1 + 64 + lane], acc1);
  }
  float v0 = acc0 + b1[lane];
  float v1 = acc1 + b1[64 + lane];
  out1[(size_t)i*D1 + lane]      = v0 > 0.f ? v0 : expm1f(v0);
  out1[(size_t)i*D1 + 64 + lane] = v1 > 0.f ? v1 : expm1f(v1);
}

// ---------------- layer-2 projection + alphas ----------------
__global__ __launch_bounds__(256) void layer2_proj_kernel(
    const float* __restrict__ out1, const float* __restrict__ W2,
    const float* __restrict__ asrc2, const float* __restrict__ adst2,
    float* __restrict__ h2, float* __restrict__ as2, float* __restrict__ ad2) {
  __shared__ float w_s[D1*CLS];
  for (int l = threadIdx.x; l < D1*CLS; l += 256) w_s[l] = W2[l];
  __syncthreads();
  int warp = threadIdx.x >> 6, lane = threadIdx.x & 63;
  int i = blockIdx.x*4 + warp;
  if (i >= NNODES) return;
  int c = lane & 15, kq = lane >> 4;  // kq in 0..3, each covers 32 k's
  float acc = 0.f;
  const float* xp = out1 + (size_t)i*D1 + kq*32;
  #pragma unroll
  for (int kk=0; kk<32; kk++)
    acc = fmaf(xp[kk], w_s[(kq*32+kk)*CLS + c], acc);
  acc += __shfl_xor(acc, 16, 64);
  acc += __shfl_xor(acc, 32, 64);
  if (lane < 16) h2[(size_t)i*CLS + c] = acc;
  float s = acc * asrc2[c];
  float d = acc * adst2[c];
  #pragma unroll
  for (int off=1; off<16; off<<=1) { s += __shfl_xor(s, off, 64); d += __shfl_xor(d, off, 64); }
  if (lane == 0) { as2[i] = s; ad2[i] = d; }
}

// ---------------- layer-2 segment softmax + aggregation ----------------
__global__ __launch_bounds__(256) void agg2_kernel(
    const float* __restrict__ h2, const float* __restrict__ as2,
    const float* __restrict__ ad2, const int* __restrict__ offs,
    const int* __restrict__ srcsort, const float* __restrict__ b2,
    float* __restrict__ out) {
  int warp = threadIdx.x >> 6, lane = threadIdx.x & 63;
  int i = blockIdx.x*4 + warp;
  if (i >= NNODES) return;
  int start = offs[i], end = offs[i+1];
  float ad = ad2[i];
  float sself = lrelu(as2[i] + ad);
  float m = sself;
  for (int j = start + lane; j < end; j += 64)
    m = fmaxf(m, lrelu(as2[srcsort[j]] + ad));
  #pragma unroll
  for (int off=1; off<64; off<<=1) m = fmaxf(m, __shfl_xor(m, off, 64));
  float den = (lane==0) ? expf(sself - m) : 0.f;
  for (int j = start + lane; j < end; j += 64)
    den += expf(lrelu(as2[srcsort[j]] + ad) - m);
  #pragma unroll
  for (int off=1; off<64; off<<=1) den += __shfl_xor(den, off, 64);
  float inv = 1.f / (den + 1e-16f);
  int c = lane & 15, g = lane >> 4;
  float acc = 0.f;
  if (g == 0) acc = expf(sself - m) * inv * h2[(size_t)i*CLS + c];
  for (int j = start + g; j < end; j += 4) {
    int s = srcsort[j];
    float w = expf(lrelu(as2[s] + ad) - m) * inv;
    acc = fmaf(w, h2[(size_t)s*CLS + c], acc);
  }
  acc += __shfl_xor(acc, 16, 64);
  acc += __shfl_xor(acc, 32, 64);
  if (lane < 16) out[(size_t)i*CLS + c] = acc + b2[c];
}

extern "C" void kernel_launch(void* const* d_in, const int* in_sizes, int n_in,
                              void* d_out, int out_size, void* d_ws, size_t ws_size,
                              hipStream_t stream) {
  const float* x     = (const float*)d_in[0];
  const int*   eidx  = (const int*)d_in[1];
  const float* W1    = (const float*)d_in[2];
  const float* asrc1 = (const float*)d_in[3];
  const float* adst1 = (const float*)d_in[4];
  const float* b1    = (const float*)d_in[5];
  const float* W2    = (const float*)d_in[6];
  const float* asrc2 = (const float*)d_in[7];
  const float* adst2 = (const float*)d_in[8];
  const float* b2    = (const float*)d_in[9];
  float* out = (float*)d_out;

  const int E = in_sizes[1] / 2;
  const int* srcs = eidx;
  const int* dsts = eidx + E;

  // workspace carve-up
  char* ws = (char*)d_ws;
  size_t off = 0;
  auto alloc = [&](size_t bytes) -> void* {
    void* p = ws + off;
    off = (off + bytes + 255) & ~(size_t)255;
    return p;
  };
  float* h1      = (float*)alloc((size_t)NNODES*D1*4);
  float* out1    = (float*)alloc((size_t)NNODES*D1*4);
  float* as1     = (float*)alloc((size_t)NNODES*HH*4);
  float* ad1     = (float*)alloc((size_t)NNODES*HH*4);
  float* h2      = (float*)alloc((size_t)NNODES*CLS*4);
  float* as2     = (float*)alloc((size_t)NNODES*4);
  float* ad2     = (float*)alloc((size_t)NNODES*4);
  int*   deg     = (int*)alloc((size_t)NNODES*4);        // reused as cursor
  int*   offs    = (int*)alloc((size_t)(NNODES+1)*4);
  int*   srcsort = (int*)alloc((size_t)E*4);

  hipMemsetAsync(deg, 0, (size_t)NNODES*4, stream);

  // layer 1 projection
  gemm1_kernel<<<(NNODES+63)/64, 256, 0, stream>>>(x, W1, h1);
  alpha1_kernel<<<(NNODES*HH+255)/256, 256, 0, stream>>>(h1, asrc1, adst1, as1, ad1);

  // CSR by dst
  count_kernel<<<(E+255)/256, 256, 0, stream>>>(dsts, deg, E);
  scan_kernel<<<1, 1024, 0, stream>>>(deg, offs);
  cursor_kernel<<<(NNODES+255)/256, 256, 0, stream>>>(offs, deg);
  place_kernel<<<(E+255)/256, 256, 0, stream>>>(srcs, dsts, deg, srcsort, E);

  // layer 1 attention + aggregation (+bias+ELU)
  agg1_kernel<<<(NNODES+3)/4, 256, 0, stream>>>(h1, as1, ad1, offs, srcsort, b1, out1);

  // layer 2
  layer2_proj_kernel<<<(NNODES+3)/4, 256, 0, stream>>>(out1, W2, asrc2, adst2, h2, as2, ad2);
  agg2_kernel<<<(NNODES+3)/4, 256, 0, stream>>>(h2, as2, ad2, offs, srcsort, b2, out);
}

// Round 4
// 279.227 us; speedup vs baseline: 1.5637x; 1.5637x over previous
//
#include <hip/hip_runtime.h>
#include <hip/hip_bf16.h>
#include <math.h>

#define NNODES 50000
#define FIN 256
#define HH 4
#define CC 32
#define D1 128   // H*C
#define CLS 16
#define NB ((NNODES + 1023) / 1024)   // 49 scan blocks

__device__ __forceinline__ float lrelu(float x){ return x > 0.f ? x : 0.2f*x; }

__device__ __forceinline__ unsigned short f2bu(float x){
  __hip_bfloat16 h = __float2bfloat16(x);
  return *reinterpret_cast<unsigned short*>(&h);
}
__device__ __forceinline__ unsigned int pbf(float a, float b){
  return (unsigned int)f2bu(a) | ((unsigned int)f2bu(b) << 16);
}
__device__ __forceinline__ float2 bf2x(unsigned int u){
  float2 r;
  r.x = __uint_as_float(u << 16);
  r.y = __uint_as_float(u & 0xffff0000u);
  return r;
}

// ---------------- GEMM1: h1 = x @ W1, also bf16 copy h1b ----------------
__global__ __launch_bounds__(256) void gemm1_kernel(const float* __restrict__ x,
                                                    const float* __restrict__ W,
                                                    float* __restrict__ h1,
                                                    unsigned int* __restrict__ h1b) {
  __shared__ float xs[32][64];
  __shared__ float ws[32][128];
  int r0 = blockIdx.x * 64;
  int tid = threadIdx.x;
  int tx = tid & 15, ty = tid >> 4;
  float acc[4][8];
  #pragma unroll
  for (int i=0;i<4;i++)
    #pragma unroll
    for (int j=0;j<8;j++) acc[i][j]=0.f;
  for (int k0 = 0; k0 < FIN; k0 += 32) {
    {
      int row = tid >> 3, kq = tid & 7;
      #pragma unroll
      for (int rr = 0; rr < 2; rr++) {
        int r = row + rr*32;
        int gr = r0 + r;
        float4 v = make_float4(0.f,0.f,0.f,0.f);
        if (gr < NNODES) v = *(const float4*)(x + (size_t)gr*FIN + k0 + kq*4);
        xs[kq*4+0][r] = v.x; xs[kq*4+1][r] = v.y;
        xs[kq*4+2][r] = v.z; xs[kq*4+3][r] = v.w;
      }
    }
    #pragma unroll
    for (int it=0; it<4; it++) {
      int l = it*1024 + tid*4;
      int k = l >> 7, c = l & 127;
      float4 v = *(const float4*)(W + (size_t)(k0+k)*D1 + c);
      *(float4*)(&ws[k][c]) = v;
    }
    __syncthreads();
    #pragma unroll
    for (int k=0;k<32;k++) {
      float xv[4], wv[8];
      #pragma unroll
      for (int i=0;i<4;i++) xv[i] = xs[k][ty*4+i];
      #pragma unroll
      for (int j=0;j<8;j++) wv[j] = ws[k][tx*8+j];
      #pragma unroll
      for (int i=0;i<4;i++)
        #pragma unroll
        for (int j=0;j<8;j++)
          acc[i][j] = fmaf(xv[i], wv[j], acc[i][j]);
    }
    __syncthreads();
  }
  #pragma unroll
  for (int i=0;i<4;i++) {
    int gr = r0 + ty*4 + i;
    if (gr < NNODES) {
      #pragma unroll
      for (int j=0;j<8;j+=4) {
        float4 v = make_float4(acc[i][j],acc[i][j+1],acc[i][j+2],acc[i][j+3]);
        *(float4*)(h1 + (size_t)gr*D1 + tx*8 + j) = v;
      }
      uint4 uv;
      uv.x = pbf(acc[i][0], acc[i][1]);
      uv.y = pbf(acc[i][2], acc[i][3]);
      uv.z = pbf(acc[i][4], acc[i][5]);
      uv.w = pbf(acc[i][6], acc[i][7]);
      *(uint4*)(h1b + (size_t)gr*(D1/2) + tx*4) = uv;
    }
  }
}

// ---------------- per-node alpha for layer 1 (fp32 h1) ----------------
__global__ void alpha1_kernel(const float* __restrict__ h1,
                              const float* __restrict__ asrc,
                              const float* __restrict__ adst,
                              float* __restrict__ as1, float* __restrict__ ad1) {
  int t = blockIdx.x * blockDim.x + threadIdx.x;  // i*H + h
  if (t >= NNODES*HH) return;
  int i = t >> 2, h = t & 3;
  const float* hp = h1 + (size_t)i*D1 + h*CC;
  const float* ap = asrc + h*CC;
  const float* bp = adst + h*CC;
  float s=0.f, d=0.f;
  #pragma unroll
  for (int c=0;c<CC;c++){ float v = hp[c]; s = fmaf(v, ap[c], s); d = fmaf(v, bp[c], d); }
  as1[t] = s; ad1[t] = d;
}

// ---------------- CSR build (by dst) ----------------
__global__ void count_kernel(const int* __restrict__ dsts, int* deg, int E) {
  int e = blockIdx.x*blockDim.x + threadIdx.x;
  if (e < E) atomicAdd(&deg[dsts[e]], 1);
}

__global__ __launch_bounds__(1024) void blocksum_kernel(const int* __restrict__ deg,
                                                        int* __restrict__ bsum) {
  int i = blockIdx.x*1024 + threadIdx.x;
  int v = (i < NNODES) ? deg[i] : 0;
  #pragma unroll
  for (int off=1; off<64; off<<=1) v += __shfl_xor(v, off, 64);
  __shared__ int wsum[16];
  int wv = threadIdx.x >> 6, ln = threadIdx.x & 63;
  if (ln == 0) wsum[wv] = v;
  __syncthreads();
  if (threadIdx.x == 0) {
    int s = 0;
    #pragma unroll
    for (int k=0;k<16;k++) s += wsum[k];
    bsum[blockIdx.x] = s;
  }
}

__global__ void scanbase_kernel(const int* __restrict__ bsum, int* __restrict__ bbase) {
  int l = threadIdx.x;                  // one wave of 64, NB<=64
  int orig = (l < NB) ? bsum[l] : 0;
  int v = orig;
  #pragma unroll
  for (int off=1; off<64; off<<=1) { int t = __shfl_up(v, off, 64); if (l >= off) v += t; }
  if (l < NB) bbase[l] = v - orig;      // exclusive
}

__global__ __launch_bounds__(1024) void scanoffs_kernel(const int* __restrict__ deg,
                                                        const int* __restrict__ bbase,
                                                        int* __restrict__ offs,
                                                        int* __restrict__ cursor) {
  int i = blockIdx.x*1024 + threadIdx.x;
  int orig = (i < NNODES) ? deg[i] : 0;
  int v = orig;
  int ln = threadIdx.x & 63, wv = threadIdx.x >> 6;
  #pragma unroll
  for (int off=1; off<64; off<<=1) { int t = __shfl_up(v, off, 64); if (ln >= off) v += t; }
  __shared__ int wsum[16], wbase[16];
  if (ln == 63) wsum[wv] = v;
  __syncthreads();
  if (threadIdx.x == 0) {
    int s = 0;
    #pragma unroll
    for (int k=0;k<16;k++) { wbase[k] = s; s += wsum[k]; }
  }
  __syncthreads();
  int incl = bbase[blockIdx.x] + wbase[wv] + v;
  if (i < NNODES) { offs[i+1] = incl; cursor[i] = incl - orig; }
  if (i == 0) offs[0] = 0;
}

__global__ void place_kernel(const int* __restrict__ srcs, const int* __restrict__ dsts,
                             int* cursor, int* __restrict__ srcsort, int E) {
  int e = blockIdx.x*blockDim.x + threadIdx.x;
  if (e < E) {
    int d = dsts[e];
    int p = atomicAdd(&cursor[d], 1);
    srcsort[p] = srcs[e];
  }
}

// ---------------- layer-1 softmax + aggregation (+bias+ELU), bf16 gathers ----------------
__global__ __launch_bounds__(256) void agg1_kernel(
    const unsigned int* __restrict__ h1b, const float* __restrict__ as1,
    const float* __restrict__ ad1, const int* __restrict__ offs,
    const int* __restrict__ srcsort, const float* __restrict__ b1,
    float* __restrict__ out1) {
  __shared__ float exs[4][4][64];   // [warp][head][chunk-slot]
  __shared__ int   ss [4][64];
  int warp = threadIdx.x >> 6;
  int lane = threadIdx.x & 63;
  int i = blockIdx.x * 4 + warp;
  if (i >= NNODES) return;
  int start = offs[i], end = offs[i+1];
  float4 adv = *(const float4*)(ad1 + (size_t)i*4);
  float4 asv = *(const float4*)(as1 + (size_t)i*4);
  float ad[4] = {adv.x, adv.y, adv.z, adv.w};
  float sself[4], m[4];
  {
    float av[4] = {asv.x, asv.y, asv.z, asv.w};
    #pragma unroll
    for (int h=0;h<4;h++) { sself[h] = lrelu(av[h] + ad[h]); m[h] = sself[h]; }
  }
  // pass1: max over incoming edges (lane-parallel)
  for (int j = start + lane; j < end; j += 64) {
    int s = srcsort[j];
    float4 a = *(const float4*)(as1 + (size_t)s*4);
    m[0] = fmaxf(m[0], lrelu(a.x + ad[0]));
    m[1] = fmaxf(m[1], lrelu(a.y + ad[1]));
    m[2] = fmaxf(m[2], lrelu(a.z + ad[2]));
    m[3] = fmaxf(m[3], lrelu(a.w + ad[3]));
  }
  #pragma unroll
  for (int off=1; off<64; off<<=1) {
    #pragma unroll
    for (int h=0;h<4;h++) m[h] = fmaxf(m[h], __shfl_xor(m[h], off, 64));
  }
  // fused: unnormalized aggregation + denominator, chunked through LDS.
  // lane owns channels {2*lane, 2*lane+1}; head hl = lane>>4.
  int hl = lane >> 4;
  float mh = m[hl];
  float den[4] = {0.f, 0.f, 0.f, 0.f};
  float accA, accB;
  {
    float wself = expf(sself[hl] - mh);
    float2 hv = bf2x(h1b[(size_t)i*(D1/2) + lane]);
    accA = wself * hv.x; accB = wself * hv.y;
  }
  for (int c0 = start; c0 < end; c0 += 64) {
    int cnt = min(64, end - c0);
    int j = c0 + lane;
    if (j < end) {
      int s = srcsort[j];
      float4 a = *(const float4*)(as1 + (size_t)s*4);
      float e0 = expf(lrelu(a.x + ad[0]) - m[0]);
      float e1 = expf(lrelu(a.y + ad[1]) - m[1]);
      float e2 = expf(lrelu(a.z + ad[2]) - m[2]);
      float e3 = expf(lrelu(a.w + ad[3]) - m[3]);
      den[0] += e0; den[1] += e1; den[2] += e2; den[3] += e3;
      exs[warp][0][lane] = e0; exs[warp][1][lane] = e1;
      exs[warp][2][lane] = e2; exs[warp][3][lane] = e3;
      ss[warp][lane] = s;
    }
    // serial over chunk (same-wave LDS, no block barrier needed)
    #pragma unroll 2
    for (int j2 = 0; j2 < cnt; j2++) {
      int s = ss[warp][j2];
      float w = exs[warp][hl][j2];
      float2 hv = bf2x(h1b[(size_t)s*(D1/2) + lane]);
      accA = fmaf(w, hv.x, accA);
      accB = fmaf(w, hv.y, accB);
    }
  }
  #pragma unroll
  for (int off=1; off<64; off<<=1) {
    #pragma unroll
    for (int h=0;h<4;h++) den[h] += __shfl_xor(den[h], off, 64);
  }
  float inv = 1.f / (den[hl] + expf(sself[hl] - mh) + 1e-16f);
  float2 bv = *(const float2*)(b1 + 2*lane);
  float v0 = accA * inv + bv.x;
  float v1 = accB * inv + bv.y;
  float2 o;
  o.x = v0 > 0.f ? v0 : expm1f(v0);
  o.y = v1 > 0.f ? v1 : expm1f(v1);
  *(float2*)(out1 + (size_t)i*D1 + 2*lane) = o;
}

// ---------------- layer-2 projection + alphas (h2 stored bf16) ----------------
__global__ __launch_bounds__(256) void layer2_proj_kernel(
    const float* __restrict__ out1, const float* __restrict__ W2,
    const float* __restrict__ asrc2, const float* __restrict__ adst2,
    __hip_bfloat16* __restrict__ h2b, float* __restrict__ as2, float* __restrict__ ad2) {
  __shared__ float w_s[D1*CLS];
  for (int l = threadIdx.x; l < D1*CLS; l += 256) w_s[l] = W2[l];
  __syncthreads();
  int warp = threadIdx.x >> 6, lane = threadIdx.x & 63;
  int i = blockIdx.x*4 + warp;
  if (i >= NNODES) return;
  int c = lane & 15, kq = lane >> 4;
  float acc = 0.f;
  const float* xp = out1 + (size_t)i*D1 + kq*32;
  #pragma unroll
  for (int kk=0; kk<32; kk++)
    acc = fmaf(xp[kk], w_s[(kq*32+kk)*CLS + c], acc);
  acc += __shfl_xor(acc, 16, 64);
  acc += __shfl_xor(acc, 32, 64);
  if (lane < 16) h2b[(size_t)i*CLS + c] = __float2bfloat16(acc);
  float s = acc * asrc2[c];
  float d = acc * adst2[c];
  #pragma unroll
  for (int off=1; off<16; off<<=1) { s += __shfl_xor(s, off, 64); d += __shfl_xor(d, off, 64); }
  if (lane == 0) { as2[i] = s; ad2[i] = d; }
}

// ---------------- layer-2 softmax + aggregation (bf16 gathers) ----------------
__global__ __launch_bounds__(256) void agg2_kernel(
    const unsigned int* __restrict__ h2b, const float* __restrict__ as2,
    const float* __restrict__ ad2, const int* __restrict__ offs,
    const int* __restrict__ srcsort, const float* __restrict__ b2,
    float* __restrict__ out) {
  int warp = threadIdx.x >> 6, lane = threadIdx.x & 63;
  int i = blockIdx.x*4 + warp;
  if (i >= NNODES) return;
  int start = offs[i], end = offs[i+1];
  float ad = ad2[i];
  float sself = lrelu(as2[i] + ad);
  float m = sself;
  for (int j = start + lane; j < end; j += 64)
    m = fmaxf(m, lrelu(as2[srcsort[j]] + ad));
  #pragma unroll
  for (int off=1; off<64; off<<=1) m = fmaxf(m, __shfl_xor(m, off, 64));
  float dp = 0.f;
  for (int j = start + lane; j < end; j += 64)
    dp += expf(lrelu(as2[srcsort[j]] + ad) - m);
  #pragma unroll
  for (int off=1; off<64; off<<=1) dp += __shfl_xor(dp, off, 64);
  float inv = 1.f / (dp + expf(sself - m) + 1e-16f);
  // 8 groups of 8 lanes; group g handles edges start+g, +8, ...
  // lane owns channels {2*cp, 2*cp+1}, cp = lane&7.
  int g = lane >> 3, cp = lane & 7;
  float2 acc = make_float2(0.f, 0.f);
  if (g == 0) {
    float w = expf(sself - m);
    float2 hv = bf2x(h2b[(size_t)i*(CLS/2) + cp]);
    acc.x = w*hv.x; acc.y = w*hv.y;
  }
  for (int j = start + g; j < end; j += 8) {
    int s = srcsort[j];
    float w = expf(lrelu(as2[s] + ad) - m);
    float2 hv = bf2x(h2b[(size_t)s*(CLS/2) + cp]);
    acc.x = fmaf(w, hv.x, acc.x);
    acc.y = fmaf(w, hv.y, acc.y);
  }
  #pragma unroll
  for (int off=8; off<64; off<<=1) {
    acc.x += __shfl_xor(acc.x, off, 64);
    acc.y += __shfl_xor(acc.y, off, 64);
  }
  if (lane < 8) {
    float2 o;
    o.x = acc.x * inv + b2[2*cp];
    o.y = acc.y * inv + b2[2*cp+1];
    *(float2*)(out + (size_t)i*CLS + 2*cp) = o;
  }
}

extern "C" void kernel_launch(void* const* d_in, const int* in_sizes, int n_in,
                              void* d_out, int out_size, void* d_ws, size_t ws_size,
                              hipStream_t stream) {
  const float* x     = (const float*)d_in[0];
  const int*   eidx  = (const int*)d_in[1];
  const float* W1    = (const float*)d_in[2];
  const float* asrc1 = (const float*)d_in[3];
  const float* adst1 = (const float*)d_in[4];
  const float* b1    = (const float*)d_in[5];
  const float* W2    = (const float*)d_in[6];
  const float* asrc2 = (const float*)d_in[7];
  const float* adst2 = (const float*)d_in[8];
  const float* b2    = (const float*)d_in[9];
  float* out = (float*)d_out;

  const int E = in_sizes[1] / 2;
  const int* srcs = eidx;
  const int* dsts = eidx + E;

  char* ws = (char*)d_ws;
  size_t off = 0;
  auto alloc = [&](size_t bytes) -> void* {
    void* p = ws + off;
    off = (off + bytes + 255) & ~(size_t)255;
    return p;
  };
  float*        h1      = (float*)alloc((size_t)NNODES*D1*4);   // aliased: out1 reuses h1
  unsigned int* h1b     = (unsigned int*)alloc((size_t)NNODES*(D1/2)*4);
  float*        as1     = (float*)alloc((size_t)NNODES*HH*4);
  float*        ad1     = (float*)alloc((size_t)NNODES*HH*4);
  __hip_bfloat16* h2b   = (__hip_bfloat16*)alloc((size_t)NNODES*CLS*2);
  float*        as2     = (float*)alloc((size_t)NNODES*4);
  float*        ad2     = (float*)alloc((size_t)NNODES*4);
  int*          deg     = (int*)alloc((size_t)NNODES*4);
  int*          cursor  = (int*)alloc((size_t)NNODES*4);
  int*          offs    = (int*)alloc((size_t)(NNODES+1)*4);
  int*          bsum    = (int*)alloc((size_t)64*4);
  int*          bbase   = (int*)alloc((size_t)64*4);
  int*          srcsort = (int*)alloc((size_t)E*4);
  float*        out1    = h1;   // fp32 h1 is dead after alpha1_kernel

  (void)hipMemsetAsync(deg, 0, (size_t)NNODES*4, stream);

  // layer 1 projection (+bf16 copy)
  gemm1_kernel<<<(NNODES+63)/64, 256, 0, stream>>>(x, W1, h1, h1b);
  alpha1_kernel<<<(NNODES*HH+255)/256, 256, 0, stream>>>(h1, asrc1, adst1, as1, ad1);

  // CSR by dst (multi-block scan)
  count_kernel<<<(E+255)/256, 256, 0, stream>>>(dsts, deg, E);
  blocksum_kernel<<<NB, 1024, 0, stream>>>(deg, bsum);
  scanbase_kernel<<<1, 64, 0, stream>>>(bsum, bbase);
  scanoffs_kernel<<<NB, 1024, 0, stream>>>(deg, bbase, offs, cursor);
  place_kernel<<<(E+255)/256, 256, 0, stream>>>(srcs, dsts, cursor, srcsort, E);

  // layer 1 attention + aggregation (+bias+ELU) — overwrites h1 as out1
  agg1_kernel<<<(NNODES+3)/4, 256, 0, stream>>>(h1b, as1, ad1, offs, srcsort, b1, out1);

  // layer 2
  layer2_proj_kernel<<<(NNODES+3)/4, 256, 0, stream>>>(out1, W2, asrc2, adst2, h2b, as2, ad2);
  agg2_kernel<<<(NNODES+3)/4, 256, 0, stream>>>((const unsigned int*)h2b, as2, ad2, offs, srcsort, b2, out);
}

// Round 5
// 244.612 us; speedup vs baseline: 1.7849x; 1.1415x over previous
//
#include <hip/hip_runtime.h>
#include <hip/hip_bf16.h>
#include <math.h>

#define NNODES 50000
#define FIN 256
#define HH 4
#define CC 32
#define D1 128   // H*C
#define CLS 16
#define NB ((NNODES + 1023) / 1024)   // 49 scan blocks

typedef __attribute__((ext_vector_type(8))) short bfrag8;   // 8 bf16 = 4 VGPRs
typedef __attribute__((ext_vector_type(4))) float facc4;

__device__ __forceinline__ float lrelu(float x){ return x > 0.f ? x : 0.2f*x; }

__device__ __forceinline__ unsigned short f2bu(float x){
  __hip_bfloat16 h = __float2bfloat16(x);
  return *reinterpret_cast<unsigned short*>(&h);
}
__device__ __forceinline__ unsigned int pbf(float a, float b){
  return (unsigned int)f2bu(a) | ((unsigned int)f2bu(b) << 16);
}
__device__ __forceinline__ float2 bf2x(unsigned int u){
  float2 r;
  r.x = __uint_as_float(u << 16);
  r.y = __uint_as_float(u & 0xffff0000u);
  return r;
}

// ---------------- W1 prep: Wt[c][k] = bf16(W1[k][c]) ----------------
__global__ void wprep_kernel(const float* __restrict__ W, unsigned short* __restrict__ Wt) {
  int t = blockIdx.x*256 + threadIdx.x;
  if (t >= FIN*D1) return;
  int k = t >> 7, c = t & 127;
  Wt[c*FIN + k] = f2bu(W[t]);
}

// ---------------- GEMM1 via MFMA: h1 = x @ W1 (bf16 inputs, fp32 acc) ----------------
// block: 64 rows x 128 cols x K=256. 4 waves; wave w owns rows w*16..w*16+15.
__global__ __launch_bounds__(256) void gemm1_mfma(const float* __restrict__ x,
                                                  const unsigned int* __restrict__ Wt,
                                                  float* __restrict__ h1) {
  __shared__ unsigned int Bs[128*256/2];    // 64 KB: Wt swizzled
  __shared__ unsigned int As[64*64/2];      // 8 KB: x tile (64 rows x 64 k) swizzled
  int tid = threadIdx.x;
  int wv = tid >> 6, lane = tid & 63;
  int r0 = blockIdx.x * 64;

  // stage all of Wt -> Bs (16B chunk w16 = c*32 + k8), XOR-swizzle byte^=(c&7)<<4
  for (int it = 0; it < 16; it++) {
    int w16 = it*256 + tid;
    int c = w16 >> 5, k8 = w16 & 31;
    uint4 v = ((const uint4*)Wt)[w16];
    int byt = (c*512 + k8*16) ^ ((c&7)<<4);
    *(uint4*)((char*)Bs + byt) = v;
  }

  facc4 acc[8];
  #pragma unroll
  for (int t=0;t<8;t++) acc[t] = (facc4){0.f,0.f,0.f,0.f};

  int arow = tid >> 2, apart = tid & 3;     // A staging: row, 64B source chunk
  int mrow = lane & 15, kb = lane >> 4;     // MFMA fragment indices

  for (int stage = 0; stage < 4; stage++) {
    // load x[r0+arow][stage*64 + apart*16 .. +15] (fp32) -> 16 bf16
    int gr = r0 + arow;
    const float* src = x + (size_t)gr*FIN + stage*64 + apart*16;
    float4 f0, f1, f2, f3;
    if (gr < NNODES) {
      f0 = *(const float4*)(src);
      f1 = *(const float4*)(src+4);
      f2 = *(const float4*)(src+8);
      f3 = *(const float4*)(src+12);
    } else {
      f0 = f1 = f2 = f3 = make_float4(0.f,0.f,0.f,0.f);
    }
    uint4 u0, u1;
    u0.x = pbf(f0.x,f0.y); u0.y = pbf(f0.z,f0.w);
    u0.z = pbf(f1.x,f1.y); u0.w = pbf(f1.z,f1.w);
    u1.x = pbf(f2.x,f2.y); u1.y = pbf(f2.z,f2.w);
    u1.z = pbf(f3.x,f3.y); u1.w = pbf(f3.z,f3.w);
    __syncthreads();   // previous stage's consumers done (also orders Bs writes once)
    int b0 = (arow*128 + apart*32) ^ ((arow&7)<<4);
    int b1 = (arow*128 + apart*32 + 16) ^ ((arow&7)<<4);
    *(uint4*)((char*)As + b0) = u0;
    *(uint4*)((char*)As + b1) = u1;
    __syncthreads();
    // 2 k-steps of 32
    #pragma unroll
    for (int ks = 0; ks < 2; ks++) {
      int row = wv*16 + mrow;
      int abyt = (row*128 + ks*64 + kb*16) ^ ((row&7)<<4);
      bfrag8 afrag = *(bfrag8*)((char*)As + abyt);
      #pragma unroll
      for (int ct = 0; ct < 8; ct++) {
        int c = ct*16 + mrow;
        int bbyt = (c*512 + stage*128 + ks*64 + kb*16) ^ ((c&7)<<4);
        bfrag8 bfrag = *(bfrag8*)((char*)Bs + bbyt);
        acc[ct] = __builtin_amdgcn_mfma_f32_16x16x32_bf16(afrag, bfrag, acc[ct], 0, 0, 0);
      }
    }
  }
  // epilogue: D layout col=lane&15, row=(lane>>4)*4+reg
  int orow0 = r0 + wv*16 + (lane>>4)*4;
  int ocol = lane & 15;
  #pragma unroll
  for (int ct=0; ct<8; ct++) {
    #pragma unroll
    for (int r=0; r<4; r++) {
      int gr = orow0 + r;
      if (gr < NNODES) h1[(size_t)gr*D1 + ct*16 + ocol] = acc[ct][r];
    }
  }
}

// ---------------- per-node alpha for layer 1 + bf16 pack of h1 ----------------
__global__ void alpha1_kernel(const float* __restrict__ h1,
                              const float* __restrict__ asrc,
                              const float* __restrict__ adst,
                              float* __restrict__ as1, float* __restrict__ ad1,
                              unsigned int* __restrict__ h1b) {
  int t = blockIdx.x * blockDim.x + threadIdx.x;  // i*H + h
  if (t >= NNODES*HH) return;
  int i = t >> 2, h = t & 3;
  const float* hp = h1 + (size_t)i*D1 + h*CC;
  const float* ap = asrc + h*CC;
  const float* bp = adst + h*CC;
  float hv[32];
  #pragma unroll
  for (int q=0;q<8;q++){
    float4 v = *(const float4*)(hp + q*4);
    hv[q*4+0]=v.x; hv[q*4+1]=v.y; hv[q*4+2]=v.z; hv[q*4+3]=v.w;
  }
  float s=0.f, d=0.f;
  #pragma unroll
  for (int c=0;c<CC;c++){ s = fmaf(hv[c], ap[c], s); d = fmaf(hv[c], bp[c], d); }
  as1[t] = s; ad1[t] = d;
  unsigned int* dst = h1b + (size_t)i*(D1/2) + h*16;
  #pragma unroll
  for (int q=0;q<4;q++){
    uint4 u;
    u.x = pbf(hv[q*8+0], hv[q*8+1]);
    u.y = pbf(hv[q*8+2], hv[q*8+3]);
    u.z = pbf(hv[q*8+4], hv[q*8+5]);
    u.w = pbf(hv[q*8+6], hv[q*8+7]);
    *(uint4*)(dst + q*4) = u;
  }
}

// ---------------- CSR build (by dst) ----------------
__global__ void count_kernel(const int* __restrict__ dsts, int* deg, int E) {
  int e = blockIdx.x*blockDim.x + threadIdx.x;
  if (e < E) atomicAdd(&deg[dsts[e]], 1);
}

__global__ __launch_bounds__(1024) void blocksum_kernel(const int* __restrict__ deg,
                                                        int* __restrict__ bsum) {
  int i = blockIdx.x*1024 + threadIdx.x;
  int v = (i < NNODES) ? deg[i] : 0;
  #pragma unroll
  for (int off=1; off<64; off<<=1) v += __shfl_xor(v, off, 64);
  __shared__ int wsum[16];
  int wv = threadIdx.x >> 6, ln = threadIdx.x & 63;
  if (ln == 0) wsum[wv] = v;
  __syncthreads();
  if (threadIdx.x == 0) {
    int s = 0;
    #pragma unroll
    for (int k=0;k<16;k++) s += wsum[k];
    bsum[blockIdx.x] = s;
  }
}

__global__ void scanbase_kernel(const int* __restrict__ bsum, int* __restrict__ bbase) {
  int l = threadIdx.x;                  // one wave of 64, NB<=64
  int orig = (l < NB) ? bsum[l] : 0;
  int v = orig;
  #pragma unroll
  for (int off=1; off<64; off<<=1) { int t = __shfl_up(v, off, 64); if (l >= off) v += t; }
  if (l < NB) bbase[l] = v - orig;      // exclusive
}

__global__ __launch_bounds__(1024) void scanoffs_kernel(const int* __restrict__ deg,
                                                        const int* __restrict__ bbase,
                                                        int* __restrict__ offs,
                                                        int* __restrict__ cursor) {
  int i = blockIdx.x*1024 + threadIdx.x;
  int orig = (i < NNODES) ? deg[i] : 0;
  int v = orig;
  int ln = threadIdx.x & 63, wv = threadIdx.x >> 6;
  #pragma unroll
  for (int off=1; off<64; off<<=1) { int t = __shfl_up(v, off, 64); if (ln >= off) v += t; }
  __shared__ int wsum[16], wbase[16];
  if (ln == 63) wsum[wv] = v;
  __syncthreads();
  if (threadIdx.x == 0) {
    int s = 0;
    #pragma unroll
    for (int k=0;k<16;k++) { wbase[k] = s; s += wsum[k]; }
  }
  __syncthreads();
  int incl = bbase[blockIdx.x] + wbase[wv] + v;
  if (i < NNODES) { offs[i+1] = incl; cursor[i] = incl - orig; }
  if (i == 0) offs[0] = 0;
}

__global__ void place_kernel(const int* __restrict__ srcs, const int* __restrict__ dsts,
                             int* cursor, int* __restrict__ srcsort, int E) {
  int e = blockIdx.x*blockDim.x + threadIdx.x;
  if (e < E) {
    int d = dsts[e];
    int p = atomicAdd(&cursor[d], 1);
    srcsort[p] = srcs[e];
  }
}

// ---------------- layer-1 softmax + aggregation (+bias+ELU), bf16 gathers ----------------
__global__ __launch_bounds__(256) void agg1_kernel(
    const unsigned int* __restrict__ h1b, const float* __restrict__ as1,
    const float* __restrict__ ad1, const int* __restrict__ offs,
    const int* __restrict__ srcsort, const float* __restrict__ b1,
    float* __restrict__ out1) {
  __shared__ float exs[4][4][64];   // [warp][head][chunk-slot]
  __shared__ int   ss [4][64];
  int warp = threadIdx.x >> 6;
  int lane = threadIdx.x & 63;
  int i = blockIdx.x * 4 + warp;
  if (i >= NNODES) return;
  int start = offs[i], end = offs[i+1];
  float4 adv = *(const float4*)(ad1 + (size_t)i*4);
  float4 asv = *(const float4*)(as1 + (size_t)i*4);
  float ad[4] = {adv.x, adv.y, adv.z, adv.w};
  float sself[4], m[4];
  {
    float av[4] = {asv.x, asv.y, asv.z, asv.w};
    #pragma unroll
    for (int h=0;h<4;h++) { sself[h] = lrelu(av[h] + ad[h]); m[h] = sself[h]; }
  }
  for (int j = start + lane; j < end; j += 64) {
    int s = srcsort[j];
    float4 a = *(const float4*)(as1 + (size_t)s*4);
    m[0] = fmaxf(m[0], lrelu(a.x + ad[0]));
    m[1] = fmaxf(m[1], lrelu(a.y + ad[1]));
    m[2] = fmaxf(m[2], lrelu(a.z + ad[2]));
    m[3] = fmaxf(m[3], lrelu(a.w + ad[3]));
  }
  #pragma unroll
  for (int off=1; off<64; off<<=1) {
    #pragma unroll
    for (int h=0;h<4;h++) m[h] = fmaxf(m[h], __shfl_xor(m[h], off, 64));
  }
  int hl = lane >> 4;
  float mh = m[hl];
  float den[4] = {0.f, 0.f, 0.f, 0.f};
  float accA, accB;
  {
    float wself = expf(sself[hl] - mh);
    float2 hv = bf2x(h1b[(size_t)i*(D1/2) + lane]);
    accA = wself * hv.x; accB = wself * hv.y;
  }
  for (int c0 = start; c0 < end; c0 += 64) {
    int cnt = min(64, end - c0);
    int j = c0 + lane;
    if (j < end) {
      int s = srcsort[j];
      float4 a = *(const float4*)(as1 + (size_t)s*4);
      float e0 = expf(lrelu(a.x + ad[0]) - m[0]);
      float e1 = expf(lrelu(a.y + ad[1]) - m[1]);
      float e2 = expf(lrelu(a.z + ad[2]) - m[2]);
      float e3 = expf(lrelu(a.w + ad[3]) - m[3]);
      den[0] += e0; den[1] += e1; den[2] += e2; den[3] += e3;
      exs[warp][0][lane] = e0; exs[warp][1][lane] = e1;
      exs[warp][2][lane] = e2; exs[warp][3][lane] = e3;
      ss[warp][lane] = s;
    }
    #pragma unroll 2
    for (int j2 = 0; j2 < cnt; j2++) {
      int s = ss[warp][j2];
      float w = exs[warp][hl][j2];
      float2 hv = bf2x(h1b[(size_t)s*(D1/2) + lane]);
      accA = fmaf(w, hv.x, accA);
      accB = fmaf(w, hv.y, accB);
    }
  }
  #pragma unroll
  for (int off=1; off<64; off<<=1) {
    #pragma unroll
    for (int h=0;h<4;h++) den[h] += __shfl_xor(den[h], off, 64);
  }
  float inv = 1.f / (den[hl] + expf(sself[hl] - mh) + 1e-16f);
  float2 bv = *(const float2*)(b1 + 2*lane);
  float v0 = accA * inv + bv.x;
  float v1 = accB * inv + bv.y;
  float2 o;
  o.x = v0 > 0.f ? v0 : expm1f(v0);
  o.y = v1 > 0.f ? v1 : expm1f(v1);
  *(float2*)(out1 + (size_t)i*D1 + 2*lane) = o;
}

// ---------------- layer-2 projection + alphas (h2 stored bf16) ----------------
__global__ __launch_bounds__(256) void layer2_proj_kernel(
    const float* __restrict__ out1, const float* __restrict__ W2,
    const float* __restrict__ asrc2, const float* __restrict__ adst2,
    __hip_bfloat16* __restrict__ h2b, float* __restrict__ as2, float* __restrict__ ad2) {
  __shared__ float w_s[D1*CLS];
  for (int l = threadIdx.x; l < D1*CLS; l += 256) w_s[l] = W2[l];
  __syncthreads();
  int warp = threadIdx.x >> 6, lane = threadIdx.x & 63;
  int i = blockIdx.x*4 + warp;
  if (i >= NNODES) return;
  int c = lane & 15, kq = lane >> 4;
  float acc = 0.f;
  const float* xp = out1 + (size_t)i*D1 + kq*32;
  #pragma unroll
  for (int kk=0; kk<32; kk++)
    acc = fmaf(xp[kk], w_s[(kq*32+kk)*CLS + c], acc);
  acc += __shfl_xor(acc, 16, 64);
  acc += __shfl_xor(acc, 32, 64);
  if (lane < 16) h2b[(size_t)i*CLS + c] = __float2bfloat16(acc);
  float s = acc * asrc2[c];
  float d = acc * adst2[c];
  #pragma unroll
  for (int off=1; off<16; off<<=1) { s += __shfl_xor(s, off, 64); d += __shfl_xor(d, off, 64); }
  if (lane == 0) { as2[i] = s; ad2[i] = d; }
}

// ---------------- layer-2 softmax + aggregation (bf16 gathers) ----------------
__global__ __launch_bounds__(256) void agg2_kernel(
    const unsigned int* __restrict__ h2b, const float* __restrict__ as2,
    const float* __restrict__ ad2, const int* __restrict__ offs,
    const int* __restrict__ srcsort, const float* __restrict__ b2,
    float* __restrict__ out) {
  int warp = threadIdx.x >> 6, lane = threadIdx.x & 63;
  int i = blockIdx.x*4 + warp;
  if (i >= NNODES) return;
  int start = offs[i], end = offs[i+1];
  float ad = ad2[i];
  float sself = lrelu(as2[i] + ad);
  float m = sself;
  for (int j = start + lane; j < end; j += 64)
    m = fmaxf(m, lrelu(as2[srcsort[j]] + ad));
  #pragma unroll
  for (int off=1; off<64; off<<=1) m = fmaxf(m, __shfl_xor(m, off, 64));
  float dp = 0.f;
  for (int j = start + lane; j < end; j += 64)
    dp += expf(lrelu(as2[srcsort[j]] + ad) - m);
  #pragma unroll
  for (int off=1; off<64; off<<=1) dp += __shfl_xor(dp, off, 64);
  float inv = 1.f / (dp + expf(sself - m) + 1e-16f);
  int g = lane >> 3, cp = lane & 7;
  float2 acc = make_float2(0.f, 0.f);
  if (g == 0) {
    float w = expf(sself - m);
    float2 hv = bf2x(h2b[(size_t)i*(CLS/2) + cp]);
    acc.x = w*hv.x; acc.y = w*hv.y;
  }
  for (int j = start + g; j < end; j += 8) {
    int s = srcsort[j];
    float w = expf(lrelu(as2[s] + ad) - m);
    float2 hv = bf2x(h2b[(size_t)s*(CLS/2) + cp]);
    acc.x = fmaf(w, hv.x, acc.x);
    acc.y = fmaf(w, hv.y, acc.y);
  }
  #pragma unroll
  for (int off=8; off<64; off<<=1) {
    acc.x += __shfl_xor(acc.x, off, 64);
    acc.y += __shfl_xor(acc.y, off, 64);
  }
  if (lane < 8) {
    float2 o;
    o.x = acc.x * inv + b2[2*cp];
    o.y = acc.y * inv + b2[2*cp+1];
    *(float2*)(out + (size_t)i*CLS + 2*cp) = o;
  }
}

extern "C" void kernel_launch(void* const* d_in, const int* in_sizes, int n_in,
                              void* d_out, int out_size, void* d_ws, size_t ws_size,
                              hipStream_t stream) {
  const float* x     = (const float*)d_in[0];
  const int*   eidx  = (const int*)d_in[1];
  const float* W1    = (const float*)d_in[2];
  const float* asrc1 = (const float*)d_in[3];
  const float* adst1 = (const float*)d_in[4];
  const float* b1    = (const float*)d_in[5];
  const float* W2    = (const float*)d_in[6];
  const float* asrc2 = (const float*)d_in[7];
  const float* adst2 = (const float*)d_in[8];
  const float* b2    = (const float*)d_in[9];
  float* out = (float*)d_out;

  const int E = in_sizes[1] / 2;
  const int* srcs = eidx;
  const int* dsts = eidx + E;

  char* ws = (char*)d_ws;
  size_t off = 0;
  auto alloc = [&](size_t bytes) -> void* {
    void* p = ws + off;
    off = (off + bytes + 255) & ~(size_t)255;
    return p;
  };
  float*          h1      = (float*)alloc((size_t)NNODES*D1*4);   // aliased: out1 reuses h1
  unsigned int*   h1b     = (unsigned int*)alloc((size_t)NNODES*(D1/2)*4);
  unsigned short* Wt      = (unsigned short*)alloc((size_t)FIN*D1*2);
  float*          as1     = (float*)alloc((size_t)NNODES*HH*4);
  float*          ad1     = (float*)alloc((size_t)NNODES*HH*4);
  __hip_bfloat16* h2b     = (__hip_bfloat16*)alloc((size_t)NNODES*CLS*2);
  float*          as2     = (float*)alloc((size_t)NNODES*4);
  float*          ad2     = (float*)alloc((size_t)NNODES*4);
  int*            deg     = (int*)alloc((size_t)NNODES*4);
  int*            cursor  = (int*)alloc((size_t)NNODES*4);
  int*            offs    = (int*)alloc((size_t)(NNODES+1)*4);
  int*            bsum    = (int*)alloc((size_t)64*4);
  int*            bbase   = (int*)alloc((size_t)64*4);
  int*            srcsort = (int*)alloc((size_t)E*4);
  float*          out1    = h1;   // fp32 h1 is dead after alpha1_kernel

  (void)hipMemsetAsync(deg, 0, (size_t)NNODES*4, stream);

  // layer 1 projection via MFMA
  wprep_kernel<<<(FIN*D1+255)/256, 256, 0, stream>>>(W1, Wt);
  gemm1_mfma<<<(NNODES+63)/64, 256, 0, stream>>>(x, (const unsigned int*)Wt, h1);
  alpha1_kernel<<<(NNODES*HH+255)/256, 256, 0, stream>>>(h1, asrc1, adst1, as1, ad1, h1b);

  // CSR by dst (multi-block scan)
  count_kernel<<<(E+255)/256, 256, 0, stream>>>(dsts, deg, E);
  blocksum_kernel<<<NB, 1024, 0, stream>>>(deg, bsum);
  scanbase_kernel<<<1, 64, 0, stream>>>(bsum, bbase);
  scanoffs_kernel<<<NB, 1024, 0, stream>>>(deg, bbase, offs, cursor);
  place_kernel<<<(E+255)/256, 256, 0, stream>>>(srcs, dsts, cursor, srcsort, E);

  // layer 1 attention + aggregation (+bias+ELU) — overwrites h1 as out1
  agg1_kernel<<<(NNODES+3)/4, 256, 0, stream>>>(h1b, as1, ad1, offs, srcsort, b1, out1);

  // layer 2
  layer2_proj_kernel<<<(NNODES+3)/4, 256, 0, stream>>>(out1, W2, asrc2, adst2, h2b, as2, ad2);
  agg2_kernel<<<(NNODES+3)/4, 256, 0, stream>>>((const unsigned int*)h2b, as2, ad2, offs, srcsort, b2, out);
}

// Round 6
// 220.702 us; speedup vs baseline: 1.9783x; 1.1083x over previous
//
#include <hip/hip_runtime.h>
#include <hip/hip_bf16.h>
#include <math.h>

#define NNODES 50000
#define FIN 256
#define HH 4
#define CC 32
#define D1 128   // H*C
#define CLS 16
#define NB ((NNODES + 1023) / 1024)   // 49 scan blocks

typedef __attribute__((ext_vector_type(8))) short bfrag8;   // 8 bf16 = 4 VGPRs
typedef __attribute__((ext_vector_type(4))) float facc4;

__device__ __forceinline__ float lrelu(float x){ return x > 0.f ? x : 0.2f*x; }

__device__ __forceinline__ unsigned short f2bu(float x){
  __hip_bfloat16 h = __float2bfloat16(x);
  return *reinterpret_cast<unsigned short*>(&h);
}
__device__ __forceinline__ unsigned int pbf(float a, float b){
  return (unsigned int)f2bu(a) | ((unsigned int)f2bu(b) << 16);
}
__device__ __forceinline__ float2 bf2x(unsigned int u){
  float2 r;
  r.x = __uint_as_float(u << 16);
  r.y = __uint_as_float(u & 0xffff0000u);
  return r;
}

// ---------------- W1 prep: Wt[c][k] = bf16(W1[k][c]) ----------------
__global__ void wprep_kernel(const float* __restrict__ W, unsigned short* __restrict__ Wt) {
  int t = blockIdx.x*256 + threadIdx.x;
  if (t >= FIN*D1) return;
  int k = t >> 7, c = t & 127;
  Wt[c*FIN + k] = f2bu(W[t]);
}

// ---------------- GEMM1 via MFMA: h1b = bf16pairs(x @ W1) ----------------
// block: 64 rows x 128 cols x K=256. 4 waves; wave w owns rows w*16..w*16+15.
// h1b[i][p] packs channels (p, p+64) — p = ct*16+ocol, +64 = ct+4.
__global__ __launch_bounds__(256) void gemm1_mfma(const float* __restrict__ x,
                                                  const unsigned int* __restrict__ Wt,
                                                  unsigned int* __restrict__ h1b) {
  __shared__ unsigned int Bs[128*256/2];    // 64 KB: Wt swizzled
  __shared__ unsigned int As[64*64/2];      // 8 KB: x tile (64 rows x 64 k) swizzled
  int tid = threadIdx.x;
  int wv = tid >> 6, lane = tid & 63;
  int r0 = blockIdx.x * 64;

  // stage all of Wt -> Bs (16B chunk w16 = c*32 + k8), XOR-swizzle byte^=(c&7)<<4
  for (int it = 0; it < 16; it++) {
    int w16 = it*256 + tid;
    int c = w16 >> 5, k8 = w16 & 31;
    uint4 v = ((const uint4*)Wt)[w16];
    int byt = (c*512 + k8*16) ^ ((c&7)<<4);
    *(uint4*)((char*)Bs + byt) = v;
  }

  facc4 acc[8];
  #pragma unroll
  for (int t=0;t<8;t++) acc[t] = (facc4){0.f,0.f,0.f,0.f};

  int arow = tid >> 2, apart = tid & 3;     // A staging: row, 64B source chunk
  int mrow = lane & 15, kb = lane >> 4;     // MFMA fragment indices

  for (int stage = 0; stage < 4; stage++) {
    int gr = r0 + arow;
    const float* src = x + (size_t)gr*FIN + stage*64 + apart*16;
    float4 f0, f1, f2, f3;
    if (gr < NNODES) {
      f0 = *(const float4*)(src);
      f1 = *(const float4*)(src+4);
      f2 = *(const float4*)(src+8);
      f3 = *(const float4*)(src+12);
    } else {
      f0 = f1 = f2 = f3 = make_float4(0.f,0.f,0.f,0.f);
    }
    uint4 u0, u1;
    u0.x = pbf(f0.x,f0.y); u0.y = pbf(f0.z,f0.w);
    u0.z = pbf(f1.x,f1.y); u0.w = pbf(f1.z,f1.w);
    u1.x = pbf(f2.x,f2.y); u1.y = pbf(f2.z,f2.w);
    u1.z = pbf(f3.x,f3.y); u1.w = pbf(f3.z,f3.w);
    __syncthreads();
    int b0 = (arow*128 + apart*32) ^ ((arow&7)<<4);
    int b1 = (arow*128 + apart*32 + 16) ^ ((arow&7)<<4);
    *(uint4*)((char*)As + b0) = u0;
    *(uint4*)((char*)As + b1) = u1;
    __syncthreads();
    #pragma unroll
    for (int ks = 0; ks < 2; ks++) {
      int row = wv*16 + mrow;
      int abyt = (row*128 + ks*64 + kb*16) ^ ((row&7)<<4);
      bfrag8 afrag = *(bfrag8*)((char*)As + abyt);
      #pragma unroll
      for (int ct = 0; ct < 8; ct++) {
        int c = ct*16 + mrow;
        int bbyt = (c*512 + stage*128 + ks*64 + kb*16) ^ ((c&7)<<4);
        bfrag8 bfrag = *(bfrag8*)((char*)Bs + bbyt);
        acc[ct] = __builtin_amdgcn_mfma_f32_16x16x32_bf16(afrag, bfrag, acc[ct], 0, 0, 0);
      }
    }
  }
  // epilogue: D layout col=lane&15, row=(lane>>4)*4+reg. Pack (c, c+64) pairs.
  int orow0 = r0 + wv*16 + (lane>>4)*4;
  int ocol = lane & 15;
  #pragma unroll
  for (int r=0; r<4; r++) {
    int gr = orow0 + r;
    if (gr < NNODES) {
      #pragma unroll
      for (int ct=0; ct<4; ct++)
        h1b[(size_t)gr*64 + ct*16 + ocol] = pbf(acc[ct][r], acc[ct+4][r]);
    }
  }
}

// ---------------- per-node alpha for layer 1 (reads bf16 h1b) ----------------
__global__ void alpha1_kernel(const unsigned int* __restrict__ h1b,
                              const float* __restrict__ asrc,
                              const float* __restrict__ adst,
                              float* __restrict__ as1, float* __restrict__ ad1) {
  int t = blockIdx.x * blockDim.x + threadIdx.x;  // i*H + h
  if (t >= NNODES*HH) return;
  int i = t >> 2, h = t & 3;
  const unsigned int* base = h1b + (size_t)i*64 + (h&1)*32;  // pairs p = (h&1)*32 + q
  const float* ap = asrc + h*CC;
  const float* bp = adst + h*CC;
  bool hi = (h >= 2);
  float s=0.f, d=0.f;
  #pragma unroll
  for (int q8=0; q8<8; q8++){
    uint4 u = *(const uint4*)(base + q8*4);
    float v0 = hi ? bf2x(u.x).y : bf2x(u.x).x;
    float v1 = hi ? bf2x(u.y).y : bf2x(u.y).x;
    float v2 = hi ? bf2x(u.z).y : bf2x(u.z).x;
    float v3 = hi ? bf2x(u.w).y : bf2x(u.w).x;
    int q = q8*4;
    s = fmaf(v0, ap[q+0], s); d = fmaf(v0, bp[q+0], d);
    s = fmaf(v1, ap[q+1], s); d = fmaf(v1, bp[q+1], d);
    s = fmaf(v2, ap[q+2], s); d = fmaf(v2, bp[q+2], d);
    s = fmaf(v3, ap[q+3], s); d = fmaf(v3, bp[q+3], d);
  }
  as1[t] = s; ad1[t] = d;
}

// ---------------- CSR build (by dst) ----------------
__global__ void count_kernel(const int* __restrict__ dsts, int* deg, int E) {
  int e = blockIdx.x*blockDim.x + threadIdx.x;
  if (e < E) atomicAdd(&deg[dsts[e]], 1);
}

__global__ __launch_bounds__(1024) void blocksum_kernel(const int* __restrict__ deg,
                                                        int* __restrict__ bsum) {
  int i = blockIdx.x*1024 + threadIdx.x;
  int v = (i < NNODES) ? deg[i] : 0;
  #pragma unroll
  for (int off=1; off<64; off<<=1) v += __shfl_xor(v, off, 64);
  __shared__ int wsum[16];
  int wv = threadIdx.x >> 6, ln = threadIdx.x & 63;
  if (ln == 0) wsum[wv] = v;
  __syncthreads();
  if (threadIdx.x == 0) {
    int s = 0;
    #pragma unroll
    for (int k=0;k<16;k++) s += wsum[k];
    bsum[blockIdx.x] = s;
  }
}

__global__ void scanbase_kernel(const int* __restrict__ bsum, int* __restrict__ bbase) {
  int l = threadIdx.x;                  // one wave of 64, NB<=64
  int orig = (l < NB) ? bsum[l] : 0;
  int v = orig;
  #pragma unroll
  for (int off=1; off<64; off<<=1) { int t = __shfl_up(v, off, 64); if (l >= off) v += t; }
  if (l < NB) bbase[l] = v - orig;      // exclusive
}

__global__ __launch_bounds__(1024) void scanoffs_kernel(const int* __restrict__ deg,
                                                        const int* __restrict__ bbase,
                                                        int* __restrict__ offs,
                                                        int* __restrict__ cursor) {
  int i = blockIdx.x*1024 + threadIdx.x;
  int orig = (i < NNODES) ? deg[i] : 0;
  int v = orig;
  int ln = threadIdx.x & 63, wv = threadIdx.x >> 6;
  #pragma unroll
  for (int off=1; off<64; off<<=1) { int t = __shfl_up(v, off, 64); if (ln >= off) v += t; }
  __shared__ int wsum[16], wbase[16];
  if (ln == 63) wsum[wv] = v;
  __syncthreads();
  if (threadIdx.x == 0) {
    int s = 0;
    #pragma unroll
    for (int k=0;k<16;k++) { wbase[k] = s; s += wsum[k]; }
  }
  __syncthreads();
  int incl = bbase[blockIdx.x] + wbase[wv] + v;
  if (i < NNODES) { offs[i+1] = incl; cursor[i] = incl - orig; }
  if (i == 0) offs[0] = 0;
}

__global__ void place_kernel(const int* __restrict__ srcs, const int* __restrict__ dsts,
                             int* cursor, int* __restrict__ srcsort, int E) {
  int e = blockIdx.x*blockDim.x + threadIdx.x;
  if (e < E) {
    int d = dsts[e];
    int p = atomicAdd(&cursor[d], 1);
    srcsort[p] = srcs[e];
  }
}

// ---------------- layer-1 softmax + aggregation (+bias+ELU), no-max softmax ----------------
// lane owns channels {lane, lane+64}; heads hlo=lane>>5, hhi=hlo+2.
__global__ __launch_bounds__(256) void agg1_kernel(
    const unsigned int* __restrict__ h1b, const float* __restrict__ as1,
    const float* __restrict__ ad1, const int* __restrict__ offs,
    const int* __restrict__ srcsort, const float* __restrict__ b1,
    float* __restrict__ out1) {
  __shared__ float exs[4][4][64];   // [warp][head][chunk-slot]
  __shared__ int   ss [4][64];
  int warp = threadIdx.x >> 6;
  int lane = threadIdx.x & 63;
  int i = blockIdx.x * 4 + warp;
  if (i >= NNODES) return;
  int start = offs[i], end = offs[i+1];
  float4 adv = *(const float4*)(ad1 + (size_t)i*4);
  float4 asv = *(const float4*)(as1 + (size_t)i*4);
  float ad[4] = {adv.x, adv.y, adv.z, adv.w};
  float wself[4];
  {
    float av[4] = {asv.x, asv.y, asv.z, asv.w};
    #pragma unroll
    for (int h=0;h<4;h++) wself[h] = expf(lrelu(av[h] + ad[h]));
  }
  int hlo = lane >> 5, hhi = hlo + 2;
  float den[4] = {0.f, 0.f, 0.f, 0.f};
  float accA, accB;
  {
    float2 hv = bf2x(h1b[(size_t)i*64 + lane]);
    accA = wself[hlo] * hv.x; accB = wself[hhi] * hv.y;
  }
  for (int c0 = start; c0 < end; c0 += 64) {
    int cnt = min(64, end - c0);
    int j = c0 + lane;
    if (j < end) {
      int s = srcsort[j];
      float4 a = *(const float4*)(as1 + (size_t)s*4);
      float e0 = expf(lrelu(a.x + ad[0]));
      float e1 = expf(lrelu(a.y + ad[1]));
      float e2 = expf(lrelu(a.z + ad[2]));
      float e3 = expf(lrelu(a.w + ad[3]));
      den[0] += e0; den[1] += e1; den[2] += e2; den[3] += e3;
      exs[warp][0][lane] = e0; exs[warp][1][lane] = e1;
      exs[warp][2][lane] = e2; exs[warp][3][lane] = e3;
      ss[warp][lane] = s;
    }
    #pragma unroll 2
    for (int j2 = 0; j2 < cnt; j2++) {
      int s = ss[warp][j2];
      float2 hv = bf2x(h1b[(size_t)s*64 + lane]);
      accA = fmaf(exs[warp][hlo][j2], hv.x, accA);
      accB = fmaf(exs[warp][hhi][j2], hv.y, accB);
    }
  }
  #pragma unroll
  for (int off=1; off<64; off<<=1) {
    #pragma unroll
    for (int h=0;h<4;h++) den[h] += __shfl_xor(den[h], off, 64);
  }
  float invlo = 1.f / (den[hlo] + wself[hlo] + 1e-16f);
  float invhi = 1.f / (den[hhi] + wself[hhi] + 1e-16f);
  float v0 = accA * invlo + b1[lane];
  float v1 = accB * invhi + b1[lane + 64];
  out1[(size_t)i*D1 + lane]      = v0 > 0.f ? v0 : expm1f(v0);
  out1[(size_t)i*D1 + 64 + lane] = v1 > 0.f ? v1 : expm1f(v1);
}

// ---------------- layer-2 projection + alphas (h2 stored bf16) ----------------
__global__ __launch_bounds__(256) void layer2_proj_kernel(
    const float* __restrict__ out1, const float* __restrict__ W2,
    const float* __restrict__ asrc2, const float* __restrict__ adst2,
    __hip_bfloat16* __restrict__ h2b, float* __restrict__ as2, float* __restrict__ ad2) {
  __shared__ float w_s[D1*CLS];
  for (int l = threadIdx.x; l < D1*CLS; l += 256) w_s[l] = W2[l];
  __syncthreads();
  int warp = threadIdx.x >> 6, lane = threadIdx.x & 63;
  int i = blockIdx.x*4 + warp;
  if (i >= NNODES) return;
  int c = lane & 15, kq = lane >> 4;
  float acc = 0.f;
  const float* xp = out1 + (size_t)i*D1 + kq*32;
  #pragma unroll
  for (int q=0; q<8; q++) {
    float4 v = *(const float4*)(xp + q*4);
    int k = kq*32 + q*4;
    acc = fmaf(v.x, w_s[(k+0)*CLS + c], acc);
    acc = fmaf(v.y, w_s[(k+1)*CLS + c], acc);
    acc = fmaf(v.z, w_s[(k+2)*CLS + c], acc);
    acc = fmaf(v.w, w_s[(k+3)*CLS + c], acc);
  }
  acc += __shfl_xor(acc, 16, 64);
  acc += __shfl_xor(acc, 32, 64);
  if (lane < 16) h2b[(size_t)i*CLS + c] = __float2bfloat16(acc);
  float s = acc * asrc2[c];
  float d = acc * adst2[c];
  #pragma unroll
  for (int off=1; off<16; off<<=1) { s += __shfl_xor(s, off, 64); d += __shfl_xor(d, off, 64); }
  if (lane == 0) { as2[i] = s; ad2[i] = d; }
}

// ---------------- layer-2 softmax + aggregation, single pass ----------------
__global__ __launch_bounds__(256) void agg2_kernel(
    const unsigned int* __restrict__ h2b, const float* __restrict__ as2,
    const float* __restrict__ ad2, const int* __restrict__ offs,
    const int* __restrict__ srcsort, const float* __restrict__ b2,
    float* __restrict__ out) {
  int warp = threadIdx.x >> 6, lane = threadIdx.x & 63;
  int i = blockIdx.x*4 + warp;
  if (i >= NNODES) return;
  int start = offs[i], end = offs[i+1];
  float ad = ad2[i];
  float wself = expf(lrelu(as2[i] + ad));
  int g = lane >> 3, cp = lane & 7;
  float2 acc = make_float2(0.f, 0.f);
  float denp = 0.f;
  if (g == 0) {
    float2 hv = bf2x(h2b[(size_t)i*(CLS/2) + cp]);
    acc.x = wself*hv.x; acc.y = wself*hv.y;
    denp = wself;
  }
  for (int j = start + g; j < end; j += 8) {
    int s = srcsort[j];
    float w = expf(lrelu(as2[s] + ad));
    denp += w;
    float2 hv = bf2x(h2b[(size_t)s*(CLS/2) + cp]);
    acc.x = fmaf(w, hv.x, acc.x);
    acc.y = fmaf(w, hv.y, acc.y);
  }
  #pragma unroll
  for (int off=8; off<64; off<<=1) {
    acc.x += __shfl_xor(acc.x, off, 64);
    acc.y += __shfl_xor(acc.y, off, 64);
    denp  += __shfl_xor(denp,  off, 64);
  }
  if (lane < 8) {
    float inv = 1.f / (denp + 1e-16f);
    float2 o;
    o.x = acc.x * inv + b2[2*cp];
    o.y = acc.y * inv + b2[2*cp+1];
    *(float2*)(out + (size_t)i*CLS + 2*cp) = o;
  }
}

extern "C" void kernel_launch(void* const* d_in, const int* in_sizes, int n_in,
                              void* d_out, int out_size, void* d_ws, size_t ws_size,
                              hipStream_t stream) {
  const float* x     = (const float*)d_in[0];
  const int*   eidx  = (const int*)d_in[1];
  const float* W1    = (const float*)d_in[2];
  const float* asrc1 = (const float*)d_in[3];
  const float* adst1 = (const float*)d_in[4];
  const float* b1    = (const float*)d_in[5];
  const float* W2    = (const float*)d_in[6];
  const float* asrc2 = (const float*)d_in[7];
  const float* adst2 = (const float*)d_in[8];
  const float* b2    = (const float*)d_in[9];
  float* out = (float*)d_out;

  const int E = in_sizes[1] / 2;
  const int* srcs = eidx;
  const int* dsts = eidx + E;

  char* ws = (char*)d_ws;
  size_t off = 0;
  auto alloc = [&](size_t bytes) -> void* {
    void* p = ws + off;
    off = (off + bytes + 255) & ~(size_t)255;
    return p;
  };
  unsigned int*   h1b     = (unsigned int*)alloc((size_t)NNODES*(D1/2)*4);
  float*          out1    = (float*)alloc((size_t)NNODES*D1*4);
  unsigned short* Wt      = (unsigned short*)alloc((size_t)FIN*D1*2);
  float*          as1     = (float*)alloc((size_t)NNODES*HH*4);
  float*          ad1     = (float*)alloc((size_t)NNODES*HH*4);
  __hip_bfloat16* h2b     = (__hip_bfloat16*)alloc((size_t)NNODES*CLS*2);
  float*          as2     = (float*)alloc((size_t)NNODES*4);
  float*          ad2     = (float*)alloc((size_t)NNODES*4);
  int*            deg     = (int*)alloc((size_t)NNODES*4);
  int*            cursor  = (int*)alloc((size_t)NNODES*4);
  int*            offs    = (int*)alloc((size_t)(NNODES+1)*4);
  int*            bsum    = (int*)alloc((size_t)64*4);
  int*            bbase   = (int*)alloc((size_t)64*4);
  int*            srcsort = (int*)alloc((size_t)E*4);

  (void)hipMemsetAsync(deg, 0, (size_t)NNODES*4, stream);

  // layer 1 projection via MFMA (writes bf16 pairs only)
  wprep_kernel<<<(FIN*D1+255)/256, 256, 0, stream>>>(W1, Wt);
  gemm1_mfma<<<(NNODES+63)/64, 256, 0, stream>>>(x, (const unsigned int*)Wt, h1b);
  alpha1_kernel<<<(NNODES*HH+255)/256, 256, 0, stream>>>(h1b, asrc1, adst1, as1, ad1);

  // CSR by dst (multi-block scan)
  count_kernel<<<(E+255)/256, 256, 0, stream>>>(dsts, deg, E);
  blocksum_kernel<<<NB, 1024, 0, stream>>>(deg, bsum);
  scanbase_kernel<<<1, 64, 0, stream>>>(bsum, bbase);
  scanoffs_kernel<<<NB, 1024, 0, stream>>>(deg, bbase, offs, cursor);
  place_kernel<<<(E+255)/256, 256, 0, stream>>>(srcs, dsts, cursor, srcsort, E);

  // layer 1 attention + aggregation (+bias+ELU)
  agg1_kernel<<<(NNODES+3)/4, 256, 0, stream>>>(h1b, as1, ad1, offs, srcsort, b1, out1);

  // layer 2
  layer2_proj_kernel<<<(NNODES+3)/4, 256, 0, stream>>>(out1, W2, asrc2, adst2, h2b, as2, ad2);
  agg2_kernel<<<(NNODES+3)/4, 256, 0, stream>>>((const unsigned int*)h2b, as2, ad2, offs, srcsort, b2, out);
}